// Round 4
// baseline (1882.888 us; speedup 1.0000x reference)
//
#include <hip/hip_runtime.h>
#include <stdint.h>

// Block-sparse linear: out[8192,4096] = x @ W^T + bias, W BSR 64x64 blocks.
// R4: 4-way block-row grouping. In this structure cols(r) = all 32 blocks of
// r's parity, so rows base+{0,2,4,6} share identical col sets -> one 32KB
// A-tile feeds N=256. Staged bytes/FLOP 0.0114 -> 0.0076 (R2/R3 showed time
// tracks staged bytes). Generic-BSR correct via runtime 4-list merge +
// per-wave predication. Block 1024 thr = 16 waves, LDS 64KB (2 blocks/CU).
// cvt kernels widened to 16B stores.

#define BATCH   8192
#define IN_F    4096
#define OUT_F   4096
#define BS      64
#define NROW    64
#define NNZB    2048
#define BM      256                        // batch rows per workgroup
#define LDS_A_BYTES (BM * BS * 2)          // 32768
#define LDS_B_BYTES (4 * BS * BS * 2)      // 32768 (four W blocks)

typedef float f32x4 __attribute__((ext_vector_type(4)));
typedef short s16x8 __attribute__((ext_vector_type(8)));   // 8 x bf16

__device__ __forceinline__ void async_copy16(const void* g, void* l) {
  // global -> LDS direct DMA, 16 B/lane. Per-lane ptr == uniform base+lane*16.
  __builtin_amdgcn_global_load_lds(
      (__attribute__((address_space(1))) void*)g,
      (__attribute__((address_space(3))) void*)l, 16, 0, 0);
}

__device__ __forceinline__ unsigned short f32_to_bf16(float f) {
  union { float f; uint32_t u; } v; v.f = f;
  return (unsigned short)((v.u + 0x7FFFu + ((v.u >> 16) & 1u)) >> 16);
}

// 8 floats in (two float4 loads), one 16B ushort8 store per thread.
__global__ void cvt_kernel(const float4* __restrict__ in,
                           ushort4* __restrict__ out, int n8) {
  int i = blockIdx.x * blockDim.x + threadIdx.x;
  if (i < n8) {
    float4 a = in[2 * i], b = in[2 * i + 1];
    ushort4 o0, o1;
    o0.x = f32_to_bf16(a.x); o0.y = f32_to_bf16(a.y);
    o0.z = f32_to_bf16(a.z); o0.w = f32_to_bf16(a.w);
    o1.x = f32_to_bf16(b.x); o1.y = f32_to_bf16(b.y);
    o1.z = f32_to_bf16(b.z); o1.w = f32_to_bf16(b.w);
    out[2 * i] = o0; out[2 * i + 1] = o1;   // adjacent 16B per thread pair
  }
}

// GEMM: grid (16 groups, BATCH/BM=32), block 1024 = 16 waves.
// Group p -> base = (p>>1)*8 + (p&1); rows base + 2*{0,1,2,3} (same parity).
// Wave w: wm = w&3 (64-row m-quarter), wn = w>>2 (row within group).
// LDS swizzle (0 conflicts since R2): chunk slot s of row r holds global
// 16B-chunk (s ^ (r&7)).
__global__ __launch_bounds__(1024) void bsr_gemm_quad_kernel(
    const unsigned short* __restrict__ xb,   // bf16 [BATCH][IN_F]
    const unsigned short* __restrict__ wb,   // bf16 [NNZB][64][64] ([n][k])
    const float* __restrict__ bias,
    const int* __restrict__ crow,
    const int* __restrict__ cols,
    float* __restrict__ out) {
  __shared__ alignas(16) char smem[LDS_A_BYTES + LDS_B_BYTES];

  const int tid = threadIdx.x;
  const int w   = tid >> 6;        // wave 0..15
  const int l   = tid & 63;        // lane
  const int wm  = w & 3;           // m-quarter
  const int wn  = w >> 2;          // row within group (0..3)
  const int p   = blockIdx.x;
  const int base = ((p >> 1) << 3) + (p & 1);
  const int m0  = blockIdx.y * BM;

  int st[4], en[4], cur[4];
#pragma unroll
  for (int j = 0; j < 4; ++j) {
    const int r = base + 2 * j;
    st[j] = crow[r]; en[j] = crow[r + 1]; cur[j] = st[j];
  }

  const int lr = l & 15;           // MFMA m/n index within 16
  const int q  = l >> 4;           // quad 0..3

  // Preload col lists into lane registers (uniform per iter via shfl).
  int cv[4];
#pragma unroll
  for (int j = 0; j < 4; ++j)
    cv[j] = (st[j] + l < en[j]) ? cols[st[j] + l] : 0;

  f32x4 acc[4][4];
#pragma unroll
  for (int mi = 0; mi < 4; ++mi)
#pragma unroll
    for (int ni = 0; ni < 4; ++ni) {
      f32x4 z = {0.f, 0.f, 0.f, 0.f};
      acc[mi][ni] = z;
    }

  // A staging: 2 issues x 16KB. chunk = it*1024+tid; arow = chunk>>3,
  // slot = tid&7, swizzled global chunk = slot ^ (arow&7).
  const int arow0 = tid >> 3;                                  // it=0 row
  const int aswz0 = ((tid & 7) ^ (arow0 & 7)) << 3;            // elements
  const int arow1 = arow0 + 128;                               // it=1 row
  const int aswz1 = ((tid & 7) ^ (arow1 & 7)) << 3;
  const unsigned short* agbase0 = xb + (size_t)(m0 + arow0) * IN_F + aswz0;
  const unsigned short* agbase1 = xb + (size_t)(m0 + arow1) * IN_F + aswz1;
  char* const alds = smem + tid * 16;                          // +it*16384
  // B staging: 2 issues x 16KB; issue it covers group rows {2it, 2it+1}.
  // brow (wave-uniform): which of the two rows this thread stages.
  const int bsel = (tid >> 9) & 1;                             // 0/1 within issue
  const int brow16 = (tid >> 3) & 63;                          // row inside W block
  const int bswz = ((tid & 7) ^ (brow16 & 7)) << 3;            // elements
  const int bgoff = (brow16 << 6) + bswz;                      // elements
  char* const blds = smem + LDS_A_BYTES + tid * 16;            // +it*16384

  while (cur[0] < en[0] || cur[1] < en[1] || cur[2] < en[2] || cur[3] < en[3]) {
    int cc[4], has[4], idx[4];
#pragma unroll
    for (int j = 0; j < 4; ++j) {
      const int o = cur[j] - st[j];
      cc[j] = (cur[j] < en[j])
                  ? ((o < 64) ? __shfl(cv[j], o) : cols[cur[j]])
                  : 0x7fffffff;
    }
    const int c = min(min(cc[0], cc[1]), min(cc[2], cc[3]));
#pragma unroll
    for (int j = 0; j < 4; ++j) {
      has[j] = (cc[j] == c);
      idx[j] = cur[j];
      cur[j] += has[j];
    }

    __syncthreads();   // previous compute done before LDS overwrite
    const size_t coff = (size_t)c * BS;
    async_copy16(agbase0 + coff, alds);
    async_copy16(agbase1 + coff, alds + 16384);
#pragma unroll
    for (int it = 0; it < 2; ++it) {       // B rows {2it+bsel}
      const int j = 2 * it + bsel;         // wave-uniform
      if (has[j])
        async_copy16(wb + ((size_t)idx[j] << 12) + bgoff, blds + it * 16384);
    }
    __syncthreads();   // drains vmcnt -> staged data visible

    const int myHas = has[wn];
    if (myHas) {
#pragma unroll
      for (int ks = 0; ks < 2; ++ks) {
        const int chunk = (((ks << 2) + q) ^ (lr & 7)) << 4;   // bytes
        s16x8 af[4], bf[4];
#pragma unroll
        for (int mi = 0; mi < 4; ++mi)   // A[m][k], swizzled chunk
          af[mi] = *(const s16x8*)(smem +
                     ((wm << 6) + (mi << 4) + lr) * 128 + chunk);
#pragma unroll
        for (int ni = 0; ni < 4; ++ni)   // B^T[n][k], region wn
          bf[ni] = *(const s16x8*)(smem + LDS_A_BYTES + (wn << 13) +
                     ((ni << 4) + lr) * 128 + chunk);
#pragma unroll
        for (int mi = 0; mi < 4; ++mi)
#pragma unroll
          for (int ni = 0; ni < 4; ++ni)
            acc[mi][ni] = __builtin_amdgcn_mfma_f32_16x16x32_bf16(
                af[mi], bf[ni], acc[mi][ni], 0, 0, 0);
      }
    }
  }

  // Epilogue: C/D layout col=lr, row=q*4+reg. Add bias, store fp32.
  const int rW = base + 2 * wn;
  const int colg = (rW << 6) + lr;
#pragma unroll
  for (int ni = 0; ni < 4; ++ni) {
    const float bv = bias[colg + (ni << 4)];
#pragma unroll
    for (int mi = 0; mi < 4; ++mi) {
      float* op = out +
          (size_t)(m0 + (wm << 6) + (mi << 4) + (q << 2)) * OUT_F +
          colg + (ni << 4);
#pragma unroll
      for (int e = 0; e < 4; ++e)
        op[(size_t)e * OUT_F] = acc[mi][ni][e] + bv;
    }
  }
}

// Safety net if ws_size < 84 MB: naive fp32, one thread per output element.
__global__ void fallback_kernel(const float* __restrict__ x,
                                const float* __restrict__ vals,
                                const float* __restrict__ bias,
                                const int* __restrict__ crow,
                                const int* __restrict__ cols,
                                float* __restrict__ out) {
  int idx = blockIdx.x * 256 + threadIdx.x;
  int m = idx >> 12;
  int n = idx & 4095;
  int r = n >> 6, nl = n & 63;
  float s = 0.f;
  int e = crow[r + 1];
  for (int i = crow[r]; i < e; ++i) {
    const float* xp = x + (size_t)m * IN_F + cols[i] * 64;
    const float* wp = vals + ((size_t)i << 12) + nl * 64;
    for (int k = 0; k < 64; ++k) s += xp[k] * wp[k];
  }
  out[idx] = s + bias[n];
}

extern "C" void kernel_launch(void* const* d_in, const int* in_sizes, int n_in,
                              void* d_out, int out_size, void* d_ws,
                              size_t ws_size, hipStream_t stream) {
  const float* x    = (const float*)d_in[0];
  const float* vals = (const float*)d_in[1];
  const float* bias = (const float*)d_in[2];
  const int*   crow = (const int*)d_in[3];
  const int*   cols = (const int*)d_in[4];
  float* out = (float*)d_out;

  const size_t x_elems = (size_t)BATCH * IN_F;       // 33.5M
  const size_t w_elems = (size_t)NNZB * BS * BS;     // 8.4M
  const size_t need = (x_elems + w_elems) * 2;       // bf16 bytes, ~84 MB

  if (ws_size >= need) {
    unsigned short* xb = (unsigned short*)d_ws;
    unsigned short* wb = xb + x_elems;
    cvt_kernel<<<(int)(x_elems / 8 / 256), 256, 0, stream>>>(
        (const float4*)x, (ushort4*)xb, (int)(x_elems / 8));
    cvt_kernel<<<(int)(w_elems / 8 / 256), 256, 0, stream>>>(
        (const float4*)vals, (ushort4*)wb, (int)(w_elems / 8));
    dim3 grid(NROW / 4, BATCH / BM);  // group-fast: x-slab stays hot in L2
    bsr_gemm_quad_kernel<<<grid, 1024, 0, stream>>>(xb, wb, bias, crow, cols,
                                                    out);
  } else {
    fallback_kernel<<<(BATCH * OUT_F) / 256, 256, 0, stream>>>(
        x, vals, bias, crow, cols, out);
  }
}